// Round 8
// baseline (1326.831 us; speedup 1.0000x reference)
//
#include <hip/hip_runtime.h>
#include <hip/hip_fp16.h>
#include <hip/hip_cooperative_groups.h>

namespace cg = cooperative_groups;

// ---------------------------------------------------------------------------
// BasketballGNN round 8: cooperative fusion, attempt 2.
//   - LDS union cut to 16.9KB (P4 scatters csr directly to global; slices are
//     XCD-local so L2 write-back merges the random 4B stores).
//   - hipLaunchCooperativeKernel return code checked; deterministic fallback
//     to the proven round-6 multi-dispatch path on error.
// ---------------------------------------------------------------------------

#define NBLK  1024   // 4 blocks/CU * 256 CUs
#define P3CAP 3200   // >= ceil(E / 256)
#define P4CAP 8192   // >= max edges per 256-node bucket (fallback kernel only)

struct Params {
    const float* x; const int* src; const int* dst;
    const float* W1; const float* b1;
    const float* W2; const float* b2;
    const float* W3; const float* b3;
    float* out;
    float* dis; int* off; int* btot; int* bbase; int* hist;
    int* bedge; int* csr; float* A; __half* H;
    int N, E, nbuckets;
};

__device__ __forceinline__ int block_scan_incl(int v, int* s, int t) {
    s[t] = v;
    __syncthreads();
#pragma unroll
    for (int d = 1; d < 256; d <<= 1) {
        int a = (t >= d) ? s[t - d] : 0;
        __syncthreads();
        s[t] += a;
        __syncthreads();
    }
    return s[t];
}

// ---------------- shared phase bodies (used by fused + standalone) ----------

template<int K, int C, int TR>
__device__ __forceinline__ void gemm_body(
    const float* __restrict__ in, const float* __restrict__ dis,
    __half* __restrict__ hp, int N, const float* Wl, int t, int tile0, int tstride)
{
    constexpr int TX = C / 4;
    constexpr int R  = (256 / TX) * TR;
    const int tx = t % TX, ty = t / TX;
    const int cb = tx * 4;
    const int ntiles = (N + R - 1) / R;

    for (int tile = tile0; tile < ntiles; tile += tstride) {
        const int row0 = tile * R + ty * TR;
        float acc[TR][4];
#pragma unroll
        for (int r = 0; r < TR; ++r) acc[r][0] = acc[r][1] = acc[r][2] = acc[r][3] = 0.0f;

        if (row0 + TR <= N) {
            const float* inp = in + (size_t)row0 * K;
#pragma unroll 4
            for (int k4 = 0; k4 < K / 4; ++k4) {
                float4 w0 = *(const float4*)&Wl[(k4 * 4 + 0) * C + cb];
                float4 w1 = *(const float4*)&Wl[(k4 * 4 + 1) * C + cb];
                float4 w2 = *(const float4*)&Wl[(k4 * 4 + 2) * C + cb];
                float4 w3 = *(const float4*)&Wl[(k4 * 4 + 3) * C + cb];
#pragma unroll
                for (int r = 0; r < TR; ++r) {
                    const float4 a = *(const float4*)&inp[r * K + k4 * 4];
                    acc[r][0] = fmaf(a.x, w0.x, acc[r][0]);
                    acc[r][1] = fmaf(a.x, w0.y, acc[r][1]);
                    acc[r][2] = fmaf(a.x, w0.z, acc[r][2]);
                    acc[r][3] = fmaf(a.x, w0.w, acc[r][3]);
                    acc[r][0] = fmaf(a.y, w1.x, acc[r][0]);
                    acc[r][1] = fmaf(a.y, w1.y, acc[r][1]);
                    acc[r][2] = fmaf(a.y, w1.z, acc[r][2]);
                    acc[r][3] = fmaf(a.y, w1.w, acc[r][3]);
                    acc[r][0] = fmaf(a.z, w2.x, acc[r][0]);
                    acc[r][1] = fmaf(a.z, w2.y, acc[r][1]);
                    acc[r][2] = fmaf(a.z, w2.z, acc[r][2]);
                    acc[r][3] = fmaf(a.z, w2.w, acc[r][3]);
                    acc[r][0] = fmaf(a.w, w3.x, acc[r][0]);
                    acc[r][1] = fmaf(a.w, w3.y, acc[r][1]);
                    acc[r][2] = fmaf(a.w, w3.z, acc[r][2]);
                    acc[r][3] = fmaf(a.w, w3.w, acc[r][3]);
                }
            }
        } else {
            for (int k = 0; k < K; ++k) {
                const float4 w4 = *(const float4*)&Wl[k * C + cb];
#pragma unroll
                for (int r = 0; r < TR; ++r) {
                    const int row = row0 + r;
                    const float a = (row < N) ? in[(size_t)row * K + k] : 0.0f;
                    acc[r][0] = fmaf(a, w4.x, acc[r][0]);
                    acc[r][1] = fmaf(a, w4.y, acc[r][1]);
                    acc[r][2] = fmaf(a, w4.z, acc[r][2]);
                    acc[r][3] = fmaf(a, w4.w, acc[r][3]);
                }
            }
        }
#pragma unroll
        for (int r = 0; r < TR; ++r) {
            const int row = row0 + r;
            if (row < N) {
                const float d = dis[row];
                __half2 h0 = __float22half2_rn(make_float2(acc[r][0] * d, acc[r][1] * d));
                __half2 h1 = __float22half2_rn(make_float2(acc[r][2] * d, acc[r][3] * d));
                uint2 u;
                u.x = *(unsigned*)&h0;
                u.y = *(unsigned*)&h1;
                *(uint2*)&hp[(size_t)row * C + cb] = u;
            }
        }
    }
}

template<int C, bool RELU>
__device__ __forceinline__ void agg_body(
    const int* __restrict__ off, const int* __restrict__ csr,
    const float* __restrict__ dis, const __half* __restrict__ hp,
    const float* __restrict__ bias, float* __restrict__ outp, int N,
    int q0, int qstride)
{
    constexpr int GL = C / 8;
    constexpr int G  = 64 / GL;
    const int wv   = threadIdx.x >> 6;
    const int lane = threadIdx.x & 63;
    const int grp  = lane / GL;
    const int gl   = lane % GL;
    const int nquads = (N + 3) / 4;

    for (int q = q0; q < nquads; q += qstride) {
        const int node = q * 4 + wv;
        if (node >= N) continue;
        const int s0 = off[node];
        const int s1 = off[node + 1];

        float acc[8]  = {0, 0, 0, 0, 0, 0, 0, 0};
        float acc2[8] = {0, 0, 0, 0, 0, 0, 0, 0};

        auto accum = [](float4 v, float* a) {
            const __half2* h2 = (const __half2*)&v;
#pragma unroll
            for (int j = 0; j < 4; ++j) {
                const float2 pr = __half22float2(h2[j]);
                a[2 * j]     += pr.x;
                a[2 * j + 1] += pr.y;
            }
        };

        if (grp == 0) {
            const float4 v = *(const float4*)&hp[(size_t)node * C + gl * 8];
            accum(v, acc);
        }
        int e = s0 + grp;
        for (; e + G < s1; e += 2 * G) {
            const int sa = csr[e];
            const int sb = csr[e + G];
            const float4 va = *(const float4*)&hp[(size_t)sa * C + gl * 8];
            const float4 vb = *(const float4*)&hp[(size_t)sb * C + gl * 8];
            accum(va, acc);
            accum(vb, acc2);
        }
        if (e < s1) {
            const int sa = csr[e];
            const float4 va = *(const float4*)&hp[(size_t)sa * C + gl * 8];
            accum(va, acc);
        }
#pragma unroll
        for (int j = 0; j < 8; ++j) acc[j] += acc2[j];

#pragma unroll
        for (int d = GL; d < 64; d <<= 1) {
#pragma unroll
            for (int j = 0; j < 8; ++j) acc[j] += __shfl_xor(acc[j], d);
        }

        if (grp == 0) {
            const float dn = dis[node];
            float v[8];
#pragma unroll
            for (int j = 0; j < 8; ++j) {
                v[j] = fmaf(dn, acc[j], bias[gl * 8 + j]);
                if (RELU) v[j] = fmaxf(v[j], 0.f);
            }
            *(float4*)&outp[(size_t)node * C + gl * 8]     = make_float4(v[0], v[1], v[2], v[3]);
            *(float4*)&outp[(size_t)node * C + gl * 8 + 4] = make_float4(v[4], v[5], v[6], v[7]);
        }
    }
}

// ---------------- fused cooperative kernel ----------------------------------

__global__ __launch_bounds__(256, 4) void fused_gnn(Params p)
{
    cg::grid_group grid = cg::this_grid();
    // LDS union: 4KB counters/scan + 12.8KB P3 stage = 16.9KB. gemm reuses
    // [0,32K)? no — gemm W tile max 32KB > union, so W tile also lives here:
    // K*C*4 = 32KB for K=128... must fit. Use separate sizing: max(16.9K, 32K).
    __shared__ __align__(16) char smem[32768];
    int* sh_a     = (int*)smem;
    int* sh_b     = (int*)(smem + 1024);
    int* sh_c     = (int*)(smem + 2048);
    int* sh_s     = (int*)(smem + 3072);
    int* sh_stage = (int*)(smem + 4096);
    float* sh_W   = (float*)smem;

    const int t   = threadIdx.x;
    const int blk = blockIdx.x;
    const int nb  = gridDim.x;
    const int N = p.N, E = p.E, nbuckets = p.nbuckets;

    // ---- P1: per-chunk bucket histogram (blocks 0..255) ----
    if (blk < 256) {
        sh_a[t] = 0;
        __syncthreads();
        const int chunk = (E + 255) / 256;
        const int e0 = blk * chunk, e1 = min(E, e0 + chunk);
        for (int e = e0 + t; e < e1; e += 256)
            atomicAdd(&sh_a[p.dst[e] >> 8], 1);
        __syncthreads();
        if (t < nbuckets) p.hist[t * 256 + blk] = sh_a[t];
    }
    grid.sync();

    // ---- P2a: per-bucket scan of per-chunk counts ----
    if (blk < nbuckets) {
        const int v = p.hist[blk * 256 + t];
        const int inc = block_scan_incl(v, sh_s, t);
        p.hist[blk * 256 + t] = inc - v;
        if (t == 255) p.btot[blk] = inc;
    }
    grid.sync();

    // ---- P2b: scan bucket totals -> bases ----
    if (blk == 0) {
        const int v = (t < nbuckets) ? p.btot[t] : 0;
        const int inc = block_scan_incl(v, sh_s, t);
        if (t < nbuckets) p.bbase[t] = inc - v;
        if (t == nbuckets - 1) p.bbase[nbuckets] = inc;
    }
    grid.sync();

    // ---- P3: LDS counting-sort partition -> bedge (blocks 0..255) ----
    if (blk < 256) {
        sh_a[t] = 0;
        __syncthreads();
        const int chunk = (E + 255) / 256;
        const int e0 = blk * chunk, e1 = min(E, e0 + chunk);
        for (int e = e0 + t; e < e1; e += 256)
            atomicAdd(&sh_a[p.dst[e] >> 8], 1);
        __syncthreads();
        const int v = sh_a[t];
        const int inc = block_scan_incl(v, sh_s, t);
        const int excl = inc - v;
        sh_c[t] = excl;
        if (t < nbuckets) sh_b[t] = p.bbase[t] + p.hist[t * 256 + blk] - excl;
        __syncthreads();
        for (int e = e0 + t; e < e1; e += 256) {
            const int dv = p.dst[e];
            const int bucket = dv >> 8;
            const int r = atomicAdd(&sh_c[bucket], 1);
            sh_stage[r] = (p.src[e] & 0xffff) | ((dv & 255) << 16) | (bucket << 24);
        }
        __syncthreads();
        const int cnt = e1 - e0;
        for (int i = t; i < cnt; i += 256) {
            const int pk = sh_stage[i];
            const int bucket = (int)((unsigned)pk >> 24);
            p.bedge[sh_b[bucket] + i] = pk;
        }
    }
    grid.sync();

    // ---- P4: per-bucket deg/dis/off + DIRECT global csr scatter ----
    if (blk < nbuckets) {
        const int e0 = p.bbase[blk], e1 = p.bbase[blk + 1];
        sh_a[t] = 0;
        __syncthreads();
        for (int e = e0 + t; e < e1; e += 256)
            atomicAdd(&sh_a[(p.bedge[e] >> 16) & 255], 1);
        __syncthreads();
        const int v = sh_a[t];
        const int inc = block_scan_incl(v, sh_s, t);
        sh_c[t] = inc - v;
        const int node = (blk << 8) + t;
        if (node < N) {
            p.off[node + 1] = e0 + inc;
            p.dis[node] = rsqrtf((float)v + 1.0f);
            if (node == 0) p.off[0] = 0;
        }
        __syncthreads();
        for (int e = e0 + t; e < e1; e += 256) {
            const int pk = p.bedge[e];
            const int pos = atomicAdd(&sh_c[(pk >> 16) & 255], 1);
            p.csr[e0 + pos] = pk & 0xffff;   // random-within-slice, XCD-local
        }
    }
    grid.sync();

    // ---- layer 1 ----
    for (int i = t; i < 128 * 64 / 4; i += 256) ((float4*)sh_W)[i] = ((const float4*)p.W1)[i];
    __syncthreads();
    gemm_body<128, 64, 2>(p.x, p.dis, p.H, N, sh_W, t, blk, nb);
    grid.sync();
    agg_body<64, true>(p.off, p.csr, p.dis, p.H, p.b1, p.A, N, blk, nb);
    grid.sync();

    // ---- layer 2 ----
    for (int i = t; i < 64 * 64 / 4; i += 256) ((float4*)sh_W)[i] = ((const float4*)p.W2)[i];
    __syncthreads();
    gemm_body<64, 64, 2>(p.A, p.dis, p.H, N, sh_W, t, blk, nb);
    grid.sync();
    agg_body<64, true>(p.off, p.csr, p.dis, p.H, p.b2, p.A, N, blk, nb);
    grid.sync();

    // ---- layer 3 ----
    for (int i = t; i < 64 * 32 / 4; i += 256) ((float4*)sh_W)[i] = ((const float4*)p.W3)[i];
    __syncthreads();
    gemm_body<64, 32, 2>(p.A, p.dis, p.H, N, sh_W, t, blk, nb);
    grid.sync();
    agg_body<32, false>(p.off, p.csr, p.dis, p.H, p.b3, p.out, N, blk, nb);
}

// ---------------- standalone fallback kernels (round-6 path) ----------------

__global__ __launch_bounds__(256) void part_hist_kernel(
    const int* __restrict__ dst, int* __restrict__ hist, int E, int nbuckets)
{
    __shared__ int lh[256];
    const int t = threadIdx.x;
    lh[t] = 0;
    __syncthreads();
    const int chunk = (E + gridDim.x - 1) / gridDim.x;
    const int e0 = blockIdx.x * chunk;
    const int e1 = min(E, e0 + chunk);
    for (int e = e0 + t; e < e1; e += 256)
        atomicAdd(&lh[dst[e] >> 8], 1);
    __syncthreads();
    if (t < nbuckets) hist[t * 256 + blockIdx.x] = lh[t];
}

__global__ __launch_bounds__(256) void part_scan_kernel(
    int* __restrict__ hist, int* __restrict__ btot)
{
    __shared__ int s[256];
    const int t = threadIdx.x;
    const int v = hist[blockIdx.x * 256 + t];
    const int inc = block_scan_incl(v, s, t);
    hist[blockIdx.x * 256 + t] = inc - v;
    if (t == 255) btot[blockIdx.x] = inc;
}

__global__ __launch_bounds__(256) void bucket_base_kernel(
    const int* __restrict__ btot, int* __restrict__ bbase, int nbuckets)
{
    __shared__ int s[256];
    const int t = threadIdx.x;
    const int v = (t < nbuckets) ? btot[t] : 0;
    const int inc = block_scan_incl(v, s, t);
    if (t < nbuckets) bbase[t] = inc - v;
    if (t == nbuckets - 1) bbase[nbuckets] = inc;
}

__global__ __launch_bounds__(256) void part_scatter_kernel(
    const int* __restrict__ src, const int* __restrict__ dst,
    const int* __restrict__ hist, const int* __restrict__ bbase,
    int* __restrict__ bedge, int E, int nbuckets)
{
    __shared__ int lh[256], gb[256], cur[256], s[256];
    __shared__ int stage[P3CAP];
    const int t = threadIdx.x;
    lh[t] = 0;
    __syncthreads();
    const int chunk = (E + gridDim.x - 1) / gridDim.x;
    const int e0 = blockIdx.x * chunk;
    const int e1 = min(E, e0 + chunk);
    for (int e = e0 + t; e < e1; e += 256)
        atomicAdd(&lh[dst[e] >> 8], 1);
    __syncthreads();
    const int v = lh[t];
    const int inc = block_scan_incl(v, s, t);
    const int excl = inc - v;
    cur[t] = excl;
    if (t < nbuckets) gb[t] = bbase[t] + hist[t * 256 + blockIdx.x] - excl;
    __syncthreads();
    for (int e = e0 + t; e < e1; e += 256) {
        const int dv = dst[e];
        const int bucket = dv >> 8;
        const int r = atomicAdd(&cur[bucket], 1);
        stage[r] = (src[e] & 0xffff) | ((dv & 255) << 16) | (bucket << 24);
    }
    __syncthreads();
    const int cnt = e1 - e0;
    for (int i = t; i < cnt; i += 256) {
        const int p = stage[i];
        const int bucket = (int)((unsigned)p >> 24);
        bedge[gb[bucket] + i] = p;
    }
}

__global__ __launch_bounds__(256) void bucket_csr_kernel(
    const int* __restrict__ bedge, const int* __restrict__ bbase,
    int* __restrict__ csr, int* __restrict__ off, float* __restrict__ dis, int N)
{
    __shared__ int deg[256], cur[256], s[256];
    __shared__ int lcsr[P4CAP];
    const int t = threadIdx.x;
    const int b = blockIdx.x;
    const int e0 = bbase[b], e1 = bbase[b + 1];
    deg[t] = 0;
    __syncthreads();
    for (int e = e0 + t; e < e1; e += 256)
        atomicAdd(&deg[(bedge[e] >> 16) & 255], 1);
    __syncthreads();
    const int v = deg[t];
    const int inc = block_scan_incl(v, s, t);
    cur[t] = inc - v;
    const int node = (b << 8) + t;
    if (node < N) {
        off[node + 1] = e0 + inc;
        dis[node] = rsqrtf((float)v + 1.0f);
        if (node == 0) off[0] = 0;
    }
    __syncthreads();
    for (int e = e0 + t; e < e1; e += 256) {
        const int p = bedge[e];
        const int pos = atomicAdd(&cur[(p >> 16) & 255], 1);
        lcsr[pos] = p & 0xffff;
    }
    __syncthreads();
    for (int i = t; i < e1 - e0; i += 256)
        csr[e0 + i] = lcsr[i];
}

template<int K, int C, int TR>
__global__ __launch_bounds__(256) void gemm_scale_kernel(
    const float* __restrict__ in, const float* __restrict__ W,
    const float* __restrict__ dis, __half* __restrict__ hp, int N)
{
    __shared__ float Wl[K * C];
    const int t = threadIdx.x;
    for (int i = t; i < K * C / 4; i += 256)
        ((float4*)Wl)[i] = ((const float4*)W)[i];
    __syncthreads();
    gemm_body<K, C, TR>(in, dis, hp, N, Wl, t, blockIdx.x, gridDim.x);
}

template<int C, bool RELU>
__global__ __launch_bounds__(256) void agg_kernel(
    const int* __restrict__ off, const int* __restrict__ csr,
    const float* __restrict__ dis, const __half* __restrict__ hp,
    const float* __restrict__ bias, float* __restrict__ out, int N)
{
    agg_body<C, RELU>(off, csr, dis, hp, bias, out, N, blockIdx.x, gridDim.x);
}

static inline size_t align_up(size_t x) { return (x + 255) & ~(size_t)255; }

extern "C" void kernel_launch(void* const* d_in, const int* in_sizes, int n_in,
                              void* d_out, int out_size, void* d_ws, size_t ws_size,
                              hipStream_t stream) {
    const float* x   = (const float*)d_in[0];
    const int*  eidx = (const int*)d_in[1];

    const int N = in_sizes[0] / 128;   // 50000 (< 65536 required for packing)
    const int E = in_sizes[1] / 2;     // 800000
    const int nbuckets = (N + 255) >> 8;

    char* ws = (char*)d_ws;
    size_t o = 0;
    float* dis   = (float*)(ws + o);  o = align_up(o + (size_t)N * 4);
    int* off     = (int*)(ws + o);    o = align_up(o + (size_t)(N + 1) * 4);
    int* btot    = (int*)(ws + o);    o = align_up(o + 256 * 4);
    int* bbase   = (int*)(ws + o);    o = align_up(o + 257 * 4);
    int* hist    = (int*)(ws + o);    o = align_up(o + 256 * 256 * 4);
    int* bedge   = (int*)(ws + o);    o = align_up(o + (size_t)E * 4);
    int* csr     = (int*)(ws + o);    o = align_up(o + (size_t)E * 4);
    float* A     = (float*)(ws + o);  o = align_up(o + (size_t)N * 64 * 4);
    __half* H    = (__half*)(ws + o); o = align_up(o + (size_t)N * 64 * 2);

    Params prm;
    prm.x = x; prm.src = eidx; prm.dst = eidx + E;
    prm.W1 = (const float*)d_in[2]; prm.b1 = (const float*)d_in[3];
    prm.W2 = (const float*)d_in[4]; prm.b2 = (const float*)d_in[5];
    prm.W3 = (const float*)d_in[6]; prm.b3 = (const float*)d_in[7];
    prm.out = (float*)d_out;
    prm.dis = dis; prm.off = off; prm.btot = btot; prm.bbase = bbase;
    prm.hist = hist; prm.bedge = bedge; prm.csr = csr; prm.A = A; prm.H = H;
    prm.N = N; prm.E = E; prm.nbuckets = nbuckets;

    void* kp[] = { &prm };
    hipError_t err = hipLaunchCooperativeKernel((const void*)fused_gnn,
                                                dim3(NBLK), dim3(256), kp, 0, stream);
    if (err == hipSuccess) return;
    (void)hipGetLastError();  // clear sticky error, take the fallback path

    // ---- fallback: proven round-6 multi-dispatch path ----
    const dim3 blk(256);
    part_hist_kernel<<<dim3(256), blk, 0, stream>>>(prm.dst, hist, E, nbuckets);
    part_scan_kernel<<<dim3(nbuckets), blk, 0, stream>>>(hist, btot);
    bucket_base_kernel<<<dim3(1), blk, 0, stream>>>(btot, bbase, nbuckets);
    part_scatter_kernel<<<dim3(256), blk, 0, stream>>>(prm.src, prm.dst, hist, bbase, bedge, E, nbuckets);
    bucket_csr_kernel<<<dim3(nbuckets), blk, 0, stream>>>(bedge, bbase, csr, off, dis, N);

    const int agg_blocks = (N + 3) / 4;
    const int g64 = (N + 31) / 32;
    const int g32 = (N + 63) / 64;

    gemm_scale_kernel<128, 64, 2><<<dim3(g64), blk, 0, stream>>>(x, prm.W1, dis, H, N);
    agg_kernel<64, true><<<dim3(agg_blocks), blk, 0, stream>>>(off, csr, dis, H, prm.b1, A, N);

    gemm_scale_kernel<64, 64, 2><<<dim3(g64), blk, 0, stream>>>(A, prm.W2, dis, H, N);
    agg_kernel<64, true><<<dim3(agg_blocks), blk, 0, stream>>>(off, csr, dis, H, prm.b2, A, N);

    gemm_scale_kernel<64, 32, 2><<<dim3(g32), blk, 0, stream>>>(A, prm.W3, dis, H, N);
    agg_kernel<32, false><<<dim3(agg_blocks), blk, 0, stream>>>(off, csr, dis, H, prm.b3, (float*)d_out, N);
}

// Round 10
// 222.612 us; speedup vs baseline: 5.9603x; 5.9603x over previous
//
#include <hip/hip_runtime.h>
#include <hip/hip_fp16.h>

// ---------------------------------------------------------------------------
// BasketballGNN round 10: round-9 with the nontemporal-load compile fix
// (__builtin_nontemporal_load requires a native clang vector type, not
// HIP_vector_type). Structure: multi-dispatch (cooperative grid.sync costs
// ~110us/sync on 8-XCD MI355X — measured R8), atomic-free bucketed CSR,
// fp16 gather table, TR=2 GEMM, 8-groups/wave agg.
// ---------------------------------------------------------------------------

#define P3CAP 3200   // >= chunk (3128 for E=800k)
#define P4CAP 8192   // >= max edges per 256-node bucket (avg 4082 for E=800k)

typedef float vf4 __attribute__((ext_vector_type(4)));   // native vector for NT loads

__device__ __forceinline__ int block_scan_incl(int v, int* s, int t) {
    s[t] = v;
    __syncthreads();
#pragma unroll
    for (int d = 1; d < 256; d <<= 1) {
        int a = (t >= d) ? s[t - d] : 0;
        __syncthreads();
        s[t] += a;
        __syncthreads();
    }
    return s[t];
}

// chunk size: ceil(E/256) rounded up to multiple of 4 (16B-aligned chunk starts)
__host__ __device__ __forceinline__ int chunk_of(int E) {
    return (((E + 255) / 256) + 3) & ~3;
}

// P1: per-chunk bucket histogram. grid=256 blocks.
__global__ __launch_bounds__(256) void part_hist_kernel(
    const int* __restrict__ dst, int* __restrict__ hist, int E, int nbuckets)
{
    __shared__ int lh[256];
    const int t = threadIdx.x;
    lh[t] = 0;
    __syncthreads();
    const int chunk = chunk_of(E);
    const int e0 = blockIdx.x * chunk;
    const int e1 = min(E, e0 + chunk);
    int e = e0 + t * 4;
    for (; e + 3 < e1; e += 1024) {
        const int4 d4 = *(const int4*)&dst[e];
        atomicAdd(&lh[d4.x >> 8], 1);
        atomicAdd(&lh[d4.y >> 8], 1);
        atomicAdd(&lh[d4.z >> 8], 1);
        atomicAdd(&lh[d4.w >> 8], 1);
    }
    for (; e < e1; ++e) atomicAdd(&lh[dst[e] >> 8], 1);
    __syncthreads();
    if (t < nbuckets) hist[t * 256 + blockIdx.x] = lh[t];
}

// P2a: per-bucket scan of the 256 per-chunk counts -> exclusive offsets + total.
__global__ __launch_bounds__(256) void part_scan_kernel(
    int* __restrict__ hist, int* __restrict__ btot)
{
    __shared__ int s[256];
    const int t = threadIdx.x;
    const int v = hist[blockIdx.x * 256 + t];
    const int inc = block_scan_incl(v, s, t);
    hist[blockIdx.x * 256 + t] = inc - v;
    if (t == 255) btot[blockIdx.x] = inc;
}

// P3: LDS counting-sort of each chunk by bucket, flush bucket-grouped runs.
// Bucket bases derived locally from btot. grid=256 blocks.
__global__ __launch_bounds__(256) void part_scatter_kernel(
    const int* __restrict__ src, const int* __restrict__ dst,
    const int* __restrict__ hist, const int* __restrict__ btot,
    int* __restrict__ bedge, int E, int nbuckets)
{
    __shared__ int lh[256], gb[256], cur[256], s[256];
    __shared__ int stage[P3CAP];
    const int t = threadIdx.x;

    // local bucket-base: exclusive scan of btot
    const int bv = (t < nbuckets) ? btot[t] : 0;
    const int binc = block_scan_incl(bv, s, t);
    const int bbase_t = binc - bv;   // exclusive prefix for bucket t
    __syncthreads();

    lh[t] = 0;
    __syncthreads();
    const int chunk = chunk_of(E);
    const int e0 = blockIdx.x * chunk;
    const int e1 = min(E, e0 + chunk);
    {
        int e = e0 + t * 4;
        for (; e + 3 < e1; e += 1024) {
            const int4 d4 = *(const int4*)&dst[e];
            atomicAdd(&lh[d4.x >> 8], 1);
            atomicAdd(&lh[d4.y >> 8], 1);
            atomicAdd(&lh[d4.z >> 8], 1);
            atomicAdd(&lh[d4.w >> 8], 1);
        }
        for (; e < e1; ++e) atomicAdd(&lh[dst[e] >> 8], 1);
    }
    __syncthreads();
    const int v = lh[t];
    const int inc = block_scan_incl(v, s, t);
    const int excl = inc - v;
    cur[t] = excl;
    if (t < nbuckets) gb[t] = bbase_t + hist[t * 256 + blockIdx.x] - excl;
    __syncthreads();
    {
        int e = e0 + t * 4;
        for (; e + 3 < e1; e += 1024) {
            const int4 d4 = *(const int4*)&dst[e];
            const int4 s4 = *(const int4*)&src[e];
            int r, b;
            b = d4.x >> 8; r = atomicAdd(&cur[b], 1);
            stage[r] = (s4.x & 0xffff) | ((d4.x & 255) << 16) | (b << 24);
            b = d4.y >> 8; r = atomicAdd(&cur[b], 1);
            stage[r] = (s4.y & 0xffff) | ((d4.y & 255) << 16) | (b << 24);
            b = d4.z >> 8; r = atomicAdd(&cur[b], 1);
            stage[r] = (s4.z & 0xffff) | ((d4.z & 255) << 16) | (b << 24);
            b = d4.w >> 8; r = atomicAdd(&cur[b], 1);
            stage[r] = (s4.w & 0xffff) | ((d4.w & 255) << 16) | (b << 24);
        }
        for (; e < e1; ++e) {
            const int dv = dst[e];
            const int b = dv >> 8;
            const int r = atomicAdd(&cur[b], 1);
            stage[r] = (src[e] & 0xffff) | ((dv & 255) << 16) | (b << 24);
        }
    }
    __syncthreads();
    const int cnt = e1 - e0;
    for (int i = t; i < cnt; i += 256) {
        const int p = stage[i];
        const int bucket = (int)((unsigned)p >> 24);
        bedge[gb[bucket] + i] = p;
    }
}

// P4: one block per bucket; bases derived locally from btot. LDS csr slice,
// emits off[] and dis[]. grid=nbuckets.
__global__ __launch_bounds__(256) void bucket_csr_kernel(
    const int* __restrict__ bedge, const int* __restrict__ btot,
    int* __restrict__ csr, int* __restrict__ off, float* __restrict__ dis,
    int N, int nbuckets)
{
    __shared__ int deg[256], cur[256], s[256];
    __shared__ int e01[2];
    __shared__ int lcsr[P4CAP];
    const int t = threadIdx.x;
    const int b = blockIdx.x;

    const int bv = (t < nbuckets) ? btot[t] : 0;
    const int binc = block_scan_incl(bv, s, t);
    if (t == b) { e01[0] = binc - bv; e01[1] = binc; }
    __syncthreads();
    const int e0 = e01[0], e1 = e01[1];

    deg[t] = 0;
    __syncthreads();
    for (int e = e0 + t; e < e1; e += 256)
        atomicAdd(&deg[(bedge[e] >> 16) & 255], 1);
    __syncthreads();
    const int v = deg[t];
    const int inc = block_scan_incl(v, s, t);
    cur[t] = inc - v;
    const int node = (b << 8) + t;
    if (node < N) {
        off[node + 1] = e0 + inc;
        dis[node] = rsqrtf((float)v + 1.0f);
        if (node == 0) off[0] = 0;
    }
    __syncthreads();
    for (int e = e0 + t; e < e1; e += 256) {
        const int p = bedge[e];
        const int pos = atomicAdd(&cur[(p >> 16) & 255], 1);
        lcsr[pos] = p & 0xffff;
    }
    __syncthreads();
    for (int i = t; i < e1 - e0; i += 256)
        csr[e0 + i] = lcsr[i];
}

// GEMM: hp[i,:] = fp16((in[i,:] @ W) * dis[i]).  TR=2 high-occupancy tile.
// Input rows are streamed once -> nontemporal loads keep L2 for the tables.
template<int K, int C, int TR>
__global__ __launch_bounds__(256) void gemm_scale_kernel(
    const float* __restrict__ in, const float* __restrict__ W,
    const float* __restrict__ dis, __half* __restrict__ hp, int N)
{
    constexpr int TX = C / 4;
    constexpr int R  = (256 / TX) * TR;
    __shared__ float Wl[K * C];

    const int t = threadIdx.x;
    for (int i = t; i < K * C / 4; i += 256)
        ((float4*)Wl)[i] = ((const float4*)W)[i];
    __syncthreads();

    const int tx = t % TX, ty = t / TX;
    const int cb = tx * 4;
    const int row0 = blockIdx.x * R + ty * TR;

    float acc[TR][4];
#pragma unroll
    for (int r = 0; r < TR; ++r) acc[r][0] = acc[r][1] = acc[r][2] = acc[r][3] = 0.0f;

    auto store_row = [&](int row, int r) {
        const float d = dis[row];
        __half2 h0 = __float22half2_rn(make_float2(acc[r][0] * d, acc[r][1] * d));
        __half2 h1 = __float22half2_rn(make_float2(acc[r][2] * d, acc[r][3] * d));
        uint2 u;
        u.x = *(unsigned*)&h0;
        u.y = *(unsigned*)&h1;
        *(uint2*)&hp[(size_t)row * C + cb] = u;
    };

    if (row0 + TR <= N) {
        const float* inp = in + (size_t)row0 * K;
#pragma unroll 4
        for (int k4 = 0; k4 < K / 4; ++k4) {
            float4 w0 = *(const float4*)&Wl[(k4 * 4 + 0) * C + cb];
            float4 w1 = *(const float4*)&Wl[(k4 * 4 + 1) * C + cb];
            float4 w2 = *(const float4*)&Wl[(k4 * 4 + 2) * C + cb];
            float4 w3 = *(const float4*)&Wl[(k4 * 4 + 3) * C + cb];
#pragma unroll
            for (int r = 0; r < TR; ++r) {
                const vf4 a = __builtin_nontemporal_load((const vf4*)&inp[r * K + k4 * 4]);
                acc[r][0] = fmaf(a.x, w0.x, acc[r][0]);
                acc[r][1] = fmaf(a.x, w0.y, acc[r][1]);
                acc[r][2] = fmaf(a.x, w0.z, acc[r][2]);
                acc[r][3] = fmaf(a.x, w0.w, acc[r][3]);
                acc[r][0] = fmaf(a.y, w1.x, acc[r][0]);
                acc[r][1] = fmaf(a.y, w1.y, acc[r][1]);
                acc[r][2] = fmaf(a.y, w1.z, acc[r][2]);
                acc[r][3] = fmaf(a.y, w1.w, acc[r][3]);
                acc[r][0] = fmaf(a.z, w2.x, acc[r][0]);
                acc[r][1] = fmaf(a.z, w2.y, acc[r][1]);
                acc[r][2] = fmaf(a.z, w2.z, acc[r][2]);
                acc[r][3] = fmaf(a.z, w2.w, acc[r][3]);
                acc[r][0] = fmaf(a.w, w3.x, acc[r][0]);
                acc[r][1] = fmaf(a.w, w3.y, acc[r][1]);
                acc[r][2] = fmaf(a.w, w3.z, acc[r][2]);
                acc[r][3] = fmaf(a.w, w3.w, acc[r][3]);
            }
        }
#pragma unroll
        for (int r = 0; r < TR; ++r) store_row(row0 + r, r);
    } else {
        for (int k = 0; k < K; ++k) {
            const float4 w4 = *(const float4*)&Wl[k * C + cb];
#pragma unroll
            for (int r = 0; r < TR; ++r) {
                const int row = row0 + r;
                const float a = (row < N) ? in[(size_t)row * K + k] : 0.0f;
                acc[r][0] = fmaf(a, w4.x, acc[r][0]);
                acc[r][1] = fmaf(a, w4.y, acc[r][1]);
                acc[r][2] = fmaf(a, w4.z, acc[r][2]);
                acc[r][3] = fmaf(a, w4.w, acc[r][3]);
            }
        }
#pragma unroll
        for (int r = 0; r < TR; ++r)
            if (row0 + r < N) store_row(row0 + r, r);
    }
}

// Aggregation over fp16 gather table. One wave per node; G = 64/(C/8) groups,
// each group a different edge row (16B/lane), unroll x2. fp32 accumulate.
template<int C, bool RELU>
__global__ __launch_bounds__(256) void agg_kernel(
    const int* __restrict__ off, const int* __restrict__ csr,
    const float* __restrict__ dis, const __half* __restrict__ hp,
    const float* __restrict__ bias, float* __restrict__ out, int N)
{
    constexpr int GL = C / 8;
    constexpr int G  = 64 / GL;
    const int wv   = threadIdx.x >> 6;
    const int lane = threadIdx.x & 63;
    const int grp  = lane / GL;
    const int gl   = lane % GL;
    const int node = blockIdx.x * 4 + wv;
    if (node >= N) return;

    const int s0 = off[node];
    const int s1 = off[node + 1];

    float acc[8]  = {0, 0, 0, 0, 0, 0, 0, 0};
    float acc2[8] = {0, 0, 0, 0, 0, 0, 0, 0};

    auto accum = [](float4 v, float* a) {
        const __half2* h2 = (const __half2*)&v;
#pragma unroll
        for (int j = 0; j < 4; ++j) {
            const float2 pr = __half22float2(h2[j]);
            a[2 * j]     += pr.x;
            a[2 * j + 1] += pr.y;
        }
    };

    if (grp == 0) {
        const float4 v = *(const float4*)&hp[(size_t)node * C + gl * 8];
        accum(v, acc);
    }
    int e = s0 + grp;
    for (; e + G < s1; e += 2 * G) {
        const int sa = csr[e];
        const int sb = csr[e + G];
        const float4 va = *(const float4*)&hp[(size_t)sa * C + gl * 8];
        const float4 vb = *(const float4*)&hp[(size_t)sb * C + gl * 8];
        accum(va, acc);
        accum(vb, acc2);
    }
    if (e < s1) {
        const int sa = csr[e];
        const float4 va = *(const float4*)&hp[(size_t)sa * C + gl * 8];
        accum(va, acc);
    }
#pragma unroll
    for (int j = 0; j < 8; ++j) acc[j] += acc2[j];

#pragma unroll
    for (int d = GL; d < 64; d <<= 1) {
#pragma unroll
        for (int j = 0; j < 8; ++j) acc[j] += __shfl_xor(acc[j], d);
    }

    if (grp == 0) {
        const float dn = dis[node];
        float v[8];
#pragma unroll
        for (int j = 0; j < 8; ++j) {
            v[j] = fmaf(dn, acc[j], bias[gl * 8 + j]);
            if (RELU) v[j] = fmaxf(v[j], 0.f);
        }
        *(float4*)&out[(size_t)node * C + gl * 8]     = make_float4(v[0], v[1], v[2], v[3]);
        *(float4*)&out[(size_t)node * C + gl * 8 + 4] = make_float4(v[4], v[5], v[6], v[7]);
    }
}

static inline size_t align_up(size_t x) { return (x + 255) & ~(size_t)255; }

extern "C" void kernel_launch(void* const* d_in, const int* in_sizes, int n_in,
                              void* d_out, int out_size, void* d_ws, size_t ws_size,
                              hipStream_t stream) {
    const float* x   = (const float*)d_in[0];
    const int*  eidx = (const int*)d_in[1];
    const float* W1  = (const float*)d_in[2];
    const float* b1  = (const float*)d_in[3];
    const float* W2  = (const float*)d_in[4];
    const float* b2  = (const float*)d_in[5];
    const float* W3  = (const float*)d_in[6];
    const float* b3  = (const float*)d_in[7];
    float* out = (float*)d_out;

    const int N = in_sizes[0] / 128;   // 50000 (< 65536 required for packing)
    const int E = in_sizes[1] / 2;     // 800000
    const int* srcp = eidx;
    const int* dstp = eidx + E;
    const int nbuckets = (N + 255) >> 8;   // 196

    char* ws = (char*)d_ws;
    size_t o = 0;
    float* dis   = (float*)(ws + o);  o = align_up(o + (size_t)N * 4);
    int* off     = (int*)(ws + o);    o = align_up(o + (size_t)(N + 1) * 4);
    int* btot    = (int*)(ws + o);    o = align_up(o + 256 * 4);
    int* hist    = (int*)(ws + o);    o = align_up(o + 256 * 256 * 4);
    int* bedge   = (int*)(ws + o);    o = align_up(o + (size_t)E * 4);
    int* csr     = (int*)(ws + o);    o = align_up(o + (size_t)E * 4);
    float* A     = (float*)(ws + o);  o = align_up(o + (size_t)N * 64 * 4);
    __half* H    = (__half*)(ws + o); o = align_up(o + (size_t)N * 64 * 2);

    const dim3 blk(256);

    // --- CSR build (no global atomics, 4 dispatches) ---
    part_hist_kernel<<<dim3(256), blk, 0, stream>>>(dstp, hist, E, nbuckets);
    part_scan_kernel<<<dim3(nbuckets), blk, 0, stream>>>(hist, btot);
    part_scatter_kernel<<<dim3(256), blk, 0, stream>>>(srcp, dstp, hist, btot, bedge, E, nbuckets);
    bucket_csr_kernel<<<dim3(nbuckets), blk, 0, stream>>>(bedge, btot, csr, off, dis, N, nbuckets);

    const int agg_blocks = (N + 3) / 4;
    const int g64 = (N + 31) / 32;   // C=64, TR=2 -> R=32
    const int g32 = (N + 63) / 64;   // C=32, TR=2 -> R=64

    // --- layer 1: x[128] @ W1 -> H (fp16); agg -> A (relu + b1) ---
    gemm_scale_kernel<128, 64, 2><<<dim3(g64), blk, 0, stream>>>(x, W1, dis, H, N);
    agg_kernel<64, true><<<dim3(agg_blocks), blk, 0, stream>>>(off, csr, dis, H, b1, A, N);

    // --- layer 2: A[64] @ W2 -> H (fp16); agg -> A (relu + b2) ---
    gemm_scale_kernel<64, 64, 2><<<dim3(g64), blk, 0, stream>>>(A, W2, dis, H, N);
    agg_kernel<64, true><<<dim3(agg_blocks), blk, 0, stream>>>(off, csr, dis, H, b2, A, N);

    // --- layer 3: A[64] @ W3 -> H (fp16, 32ch); agg -> out (+b3, no relu) ---
    gemm_scale_kernel<64, 32, 2><<<dim3(g32), blk, 0, stream>>>(A, W3, dis, H, N);
    agg_kernel<32, false><<<dim3(agg_blocks), blk, 0, stream>>>(off, csr, dis, H, b3, out, N);
}

// Round 11
// 214.963 us; speedup vs baseline: 6.1724x; 1.0356x over previous
//
#include <hip/hip_runtime.h>
#include <hip/hip_fp16.h>

// ---------------------------------------------------------------------------
// BasketballGNN round 11: fuse agg_l + relu + gemm_{l+1} (row-aligned, needs
// only a block-local barrier). Pipeline: CSR(4) + gemm1 + fused(agg1+gemm2) +
// fused(agg2+gemm3) + agg3 = 8 dispatches. Intermediate A array eliminated
// (~51MB less HBM traffic). CSR build and agg inner loop unchanged from R10.
// ---------------------------------------------------------------------------

#define P3CAP 3200   // >= chunk (3128 for E=800k)
#define P4CAP 8192   // >= max edges per 256-node bucket (avg 4082 for E=800k)

typedef float vf4 __attribute__((ext_vector_type(4)));

__device__ __forceinline__ int block_scan_incl(int v, int* s, int t) {
    s[t] = v;
    __syncthreads();
#pragma unroll
    for (int d = 1; d < 256; d <<= 1) {
        int a = (t >= d) ? s[t - d] : 0;
        __syncthreads();
        s[t] += a;
        __syncthreads();
    }
    return s[t];
}

__host__ __device__ __forceinline__ int chunk_of(int E) {
    return (((E + 255) / 256) + 3) & ~3;
}

// P1: per-chunk bucket histogram. grid=256 blocks.
__global__ __launch_bounds__(256) void part_hist_kernel(
    const int* __restrict__ dst, int* __restrict__ hist, int E, int nbuckets)
{
    __shared__ int lh[256];
    const int t = threadIdx.x;
    lh[t] = 0;
    __syncthreads();
    const int chunk = chunk_of(E);
    const int e0 = blockIdx.x * chunk;
    const int e1 = min(E, e0 + chunk);
    int e = e0 + t * 4;
    for (; e + 3 < e1; e += 1024) {
        const int4 d4 = *(const int4*)&dst[e];
        atomicAdd(&lh[d4.x >> 8], 1);
        atomicAdd(&lh[d4.y >> 8], 1);
        atomicAdd(&lh[d4.z >> 8], 1);
        atomicAdd(&lh[d4.w >> 8], 1);
    }
    for (; e < e1; ++e) atomicAdd(&lh[dst[e] >> 8], 1);
    __syncthreads();
    if (t < nbuckets) hist[t * 256 + blockIdx.x] = lh[t];
}

// P2a: per-bucket scan of the 256 per-chunk counts.
__global__ __launch_bounds__(256) void part_scan_kernel(
    int* __restrict__ hist, int* __restrict__ btot)
{
    __shared__ int s[256];
    const int t = threadIdx.x;
    const int v = hist[blockIdx.x * 256 + t];
    const int inc = block_scan_incl(v, s, t);
    hist[blockIdx.x * 256 + t] = inc - v;
    if (t == 255) btot[blockIdx.x] = inc;
}

// P3: LDS counting-sort of each chunk by bucket, flush bucket-grouped runs.
__global__ __launch_bounds__(256) void part_scatter_kernel(
    const int* __restrict__ src, const int* __restrict__ dst,
    const int* __restrict__ hist, const int* __restrict__ btot,
    int* __restrict__ bedge, int E, int nbuckets)
{
    __shared__ int lh[256], gb[256], cur[256], s[256];
    __shared__ int stage[P3CAP];
    const int t = threadIdx.x;

    const int bv = (t < nbuckets) ? btot[t] : 0;
    const int binc = block_scan_incl(bv, s, t);
    const int bbase_t = binc - bv;
    __syncthreads();

    lh[t] = 0;
    __syncthreads();
    const int chunk = chunk_of(E);
    const int e0 = blockIdx.x * chunk;
    const int e1 = min(E, e0 + chunk);
    {
        int e = e0 + t * 4;
        for (; e + 3 < e1; e += 1024) {
            const int4 d4 = *(const int4*)&dst[e];
            atomicAdd(&lh[d4.x >> 8], 1);
            atomicAdd(&lh[d4.y >> 8], 1);
            atomicAdd(&lh[d4.z >> 8], 1);
            atomicAdd(&lh[d4.w >> 8], 1);
        }
        for (; e < e1; ++e) atomicAdd(&lh[dst[e] >> 8], 1);
    }
    __syncthreads();
    const int v = lh[t];
    const int inc = block_scan_incl(v, s, t);
    const int excl = inc - v;
    cur[t] = excl;
    if (t < nbuckets) gb[t] = bbase_t + hist[t * 256 + blockIdx.x] - excl;
    __syncthreads();
    {
        int e = e0 + t * 4;
        for (; e + 3 < e1; e += 1024) {
            const int4 d4 = *(const int4*)&dst[e];
            const int4 s4 = *(const int4*)&src[e];
            int r, b;
            b = d4.x >> 8; r = atomicAdd(&cur[b], 1);
            stage[r] = (s4.x & 0xffff) | ((d4.x & 255) << 16) | (b << 24);
            b = d4.y >> 8; r = atomicAdd(&cur[b], 1);
            stage[r] = (s4.y & 0xffff) | ((d4.y & 255) << 16) | (b << 24);
            b = d4.z >> 8; r = atomicAdd(&cur[b], 1);
            stage[r] = (s4.z & 0xffff) | ((d4.z & 255) << 16) | (b << 24);
            b = d4.w >> 8; r = atomicAdd(&cur[b], 1);
            stage[r] = (s4.w & 0xffff) | ((d4.w & 255) << 16) | (b << 24);
        }
        for (; e < e1; ++e) {
            const int dv = dst[e];
            const int b = dv >> 8;
            const int r = atomicAdd(&cur[b], 1);
            stage[r] = (src[e] & 0xffff) | ((dv & 255) << 16) | (b << 24);
        }
    }
    __syncthreads();
    const int cnt = e1 - e0;
    for (int i = t; i < cnt; i += 256) {
        const int p = stage[i];
        const int bucket = (int)((unsigned)p >> 24);
        bedge[gb[bucket] + i] = p;
    }
}

// P4: one block per bucket -> csr slice, off[], dis[].
__global__ __launch_bounds__(256) void bucket_csr_kernel(
    const int* __restrict__ bedge, const int* __restrict__ btot,
    int* __restrict__ csr, int* __restrict__ off, float* __restrict__ dis,
    int N, int nbuckets)
{
    __shared__ int deg[256], cur[256], s[256];
    __shared__ int e01[2];
    __shared__ int lcsr[P4CAP];
    const int t = threadIdx.x;
    const int b = blockIdx.x;

    const int bv = (t < nbuckets) ? btot[t] : 0;
    const int binc = block_scan_incl(bv, s, t);
    if (t == b) { e01[0] = binc - bv; e01[1] = binc; }
    __syncthreads();
    const int e0 = e01[0], e1 = e01[1];

    deg[t] = 0;
    __syncthreads();
    for (int e = e0 + t; e < e1; e += 256)
        atomicAdd(&deg[(bedge[e] >> 16) & 255], 1);
    __syncthreads();
    const int v = deg[t];
    const int inc = block_scan_incl(v, s, t);
    cur[t] = inc - v;
    const int node = (b << 8) + t;
    if (node < N) {
        off[node + 1] = e0 + inc;
        dis[node] = rsqrtf((float)v + 1.0f);
        if (node == 0) off[0] = 0;
    }
    __syncthreads();
    for (int e = e0 + t; e < e1; e += 256) {
        const int p = bedge[e];
        const int pos = atomicAdd(&cur[(p >> 16) & 255], 1);
        lcsr[pos] = p & 0xffff;
    }
    __syncthreads();
    for (int i = t; i < e1 - e0; i += 256)
        csr[e0 + i] = lcsr[i];
}

// GEMM (layer 1): hp[i,:] = fp16((in[i,:] @ W) * dis[i]).  TR=2 tile.
template<int K, int C, int TR>
__global__ __launch_bounds__(256) void gemm_scale_kernel(
    const float* __restrict__ in, const float* __restrict__ W,
    const float* __restrict__ dis, __half* __restrict__ hp, int N)
{
    constexpr int TX = C / 4;
    constexpr int R  = (256 / TX) * TR;
    __shared__ float Wl[K * C];

    const int t = threadIdx.x;
    for (int i = t; i < K * C / 4; i += 256)
        ((float4*)Wl)[i] = ((const float4*)W)[i];
    __syncthreads();

    const int tx = t % TX, ty = t / TX;
    const int cb = tx * 4;
    const int row0 = blockIdx.x * R + ty * TR;

    float acc[TR][4];
#pragma unroll
    for (int r = 0; r < TR; ++r) acc[r][0] = acc[r][1] = acc[r][2] = acc[r][3] = 0.0f;

    auto store_row = [&](int row, int r) {
        const float d = dis[row];
        __half2 h0 = __float22half2_rn(make_float2(acc[r][0] * d, acc[r][1] * d));
        __half2 h1 = __float22half2_rn(make_float2(acc[r][2] * d, acc[r][3] * d));
        uint2 u;
        u.x = *(unsigned*)&h0;
        u.y = *(unsigned*)&h1;
        *(uint2*)&hp[(size_t)row * C + cb] = u;
    };

    if (row0 + TR <= N) {
        const float* inp = in + (size_t)row0 * K;
#pragma unroll 4
        for (int k4 = 0; k4 < K / 4; ++k4) {
            float4 w0 = *(const float4*)&Wl[(k4 * 4 + 0) * C + cb];
            float4 w1 = *(const float4*)&Wl[(k4 * 4 + 1) * C + cb];
            float4 w2 = *(const float4*)&Wl[(k4 * 4 + 2) * C + cb];
            float4 w3 = *(const float4*)&Wl[(k4 * 4 + 3) * C + cb];
#pragma unroll
            for (int r = 0; r < TR; ++r) {
                const vf4 a = __builtin_nontemporal_load((const vf4*)&inp[r * K + k4 * 4]);
                acc[r][0] = fmaf(a.x, w0.x, acc[r][0]);
                acc[r][1] = fmaf(a.x, w0.y, acc[r][1]);
                acc[r][2] = fmaf(a.x, w0.z, acc[r][2]);
                acc[r][3] = fmaf(a.x, w0.w, acc[r][3]);
                acc[r][0] = fmaf(a.y, w1.x, acc[r][0]);
                acc[r][1] = fmaf(a.y, w1.y, acc[r][1]);
                acc[r][2] = fmaf(a.y, w1.z, acc[r][2]);
                acc[r][3] = fmaf(a.y, w1.w, acc[r][3]);
                acc[r][0] = fmaf(a.z, w2.x, acc[r][0]);
                acc[r][1] = fmaf(a.z, w2.y, acc[r][1]);
                acc[r][2] = fmaf(a.z, w2.z, acc[r][2]);
                acc[r][3] = fmaf(a.z, w2.w, acc[r][3]);
                acc[r][0] = fmaf(a.w, w3.x, acc[r][0]);
                acc[r][1] = fmaf(a.w, w3.y, acc[r][1]);
                acc[r][2] = fmaf(a.w, w3.z, acc[r][2]);
                acc[r][3] = fmaf(a.w, w3.w, acc[r][3]);
            }
        }
#pragma unroll
        for (int r = 0; r < TR; ++r) store_row(row0 + r, r);
    } else {
        for (int k = 0; k < K; ++k) {
            const float4 w4 = *(const float4*)&Wl[k * C + cb];
#pragma unroll
            for (int r = 0; r < TR; ++r) {
                const int row = row0 + r;
                const float a = (row < N) ? in[(size_t)row * K + k] : 0.0f;
                acc[r][0] = fmaf(a, w4.x, acc[r][0]);
                acc[r][1] = fmaf(a, w4.y, acc[r][1]);
                acc[r][2] = fmaf(a, w4.z, acc[r][2]);
                acc[r][3] = fmaf(a, w4.w, acc[r][3]);
            }
        }
#pragma unroll
        for (int r = 0; r < TR; ++r)
            if (row0 + r < N) store_row(row0 + r, r);
    }
}

// Fused agg(relu,bias) + gemm_next. hp_in: fp16 64-ch table. Per block:
// NPB nodes. Phase A: each wave aggregates NPB/4 nodes (8 groups x 8 lanes,
// 16B/lane gathers, unroll x2) -> relu row into LDS Al (stride 65: kills the
// k-broadcast bank conflict). Phase B: block GEMM Al @ Wn -> fp16 hp_out.
template<int COUT>
__global__ __launch_bounds__(256) void fused_agg_gemm_kernel(
    const int* __restrict__ off, const int* __restrict__ csr,
    const float* __restrict__ dis, const __half* __restrict__ hp_in,
    const float* __restrict__ bias, const float* __restrict__ Wn,
    __half* __restrict__ hp_out, int N)
{
    constexpr int TX  = COUT / 4;    // 16 (COUT=64) or 8 (COUT=32)
    constexpr int NPB = 256 / TX;    // 16 or 32 rows per block
    constexpr int NPW = NPB / 4;     // nodes per wave: 4 or 8
    __shared__ float Wl[64 * COUT];
    __shared__ float Al[NPB * 65];

    const int t = threadIdx.x;
    for (int i = t; i < 64 * COUT / 4; i += 256)
        ((float4*)Wl)[i] = ((const float4*)Wn)[i];
    // (no sync needed until phase B; phase A never touches Wl)

    const int wv   = t >> 6;
    const int lane = t & 63;
    const int grp  = lane >> 3;   // 8 groups of 8 lanes
    const int gl   = lane & 7;

    float b[8];
#pragma unroll
    for (int j = 0; j < 8; ++j) b[j] = bias[gl * 8 + j];

    auto accum = [](float4 v, float* a) {
        const __half2* h2 = (const __half2*)&v;
#pragma unroll
        for (int j = 0; j < 4; ++j) {
            const float2 pr = __half22float2(h2[j]);
            a[2 * j]     += pr.x;
            a[2 * j + 1] += pr.y;
        }
    };

    const int node0 = blockIdx.x * NPB + wv * NPW;
    for (int nl = 0; nl < NPW; ++nl) {
        const int node = node0 + nl;
        if (node >= N) break;
        const int s0 = off[node];
        const int s1 = off[node + 1];

        float acc[8]  = {0, 0, 0, 0, 0, 0, 0, 0};
        float acc2[8] = {0, 0, 0, 0, 0, 0, 0, 0};

        if (grp == 0) {
            const float4 v = *(const float4*)&hp_in[(size_t)node * 64 + gl * 8];
            accum(v, acc);
        }
        int e = s0 + grp;
        for (; e + 8 < s1; e += 16) {
            const int sa = csr[e];
            const int sb = csr[e + 8];
            const float4 va = *(const float4*)&hp_in[(size_t)sa * 64 + gl * 8];
            const float4 vb = *(const float4*)&hp_in[(size_t)sb * 64 + gl * 8];
            accum(va, acc);
            accum(vb, acc2);
        }
        if (e < s1) {
            const int sa = csr[e];
            const float4 va = *(const float4*)&hp_in[(size_t)sa * 64 + gl * 8];
            accum(va, acc);
        }
#pragma unroll
        for (int j = 0; j < 8; ++j) acc[j] += acc2[j];
#pragma unroll
        for (int d = 8; d < 64; d <<= 1) {
#pragma unroll
            for (int j = 0; j < 8; ++j) acc[j] += __shfl_xor(acc[j], d);
        }
        if (grp == 0) {
            const float dn = dis[node];
            const int row = wv * NPW + nl;
#pragma unroll
            for (int j = 0; j < 8; ++j)
                Al[row * 65 + gl * 8 + j] = fmaxf(fmaf(dn, acc[j], b[j]), 0.0f);
        }
    }
    __syncthreads();

    // Phase B: rows = NPB, channels = COUT; thread (tx,ty) -> row ty, 4 ch.
    const int tx = t % TX, ty = t / TX;
    const int gnode = blockIdx.x * NPB + ty;
    const int cb = tx * 4;
    float c0 = 0.f, c1 = 0.f, c2 = 0.f, c3 = 0.f;
#pragma unroll 8
    for (int k = 0; k < 64; ++k) {
        const float a = Al[ty * 65 + k];
        const float4 w4 = *(const float4*)&Wl[k * COUT + cb];
        c0 = fmaf(a, w4.x, c0);
        c1 = fmaf(a, w4.y, c1);
        c2 = fmaf(a, w4.z, c2);
        c3 = fmaf(a, w4.w, c3);
    }
    if (gnode < N) {
        const float d = dis[gnode];
        __half2 h0 = __float22half2_rn(make_float2(c0 * d, c1 * d));
        __half2 h1 = __float22half2_rn(make_float2(c2 * d, c3 * d));
        uint2 u;
        u.x = *(unsigned*)&h0;
        u.y = *(unsigned*)&h1;
        *(uint2*)&hp_out[(size_t)gnode * COUT + cb] = u;
    }
}

// Final aggregation (layer 3): 32-ch fp16 table -> fp32 out, +bias, no relu.
template<int C, bool RELU>
__global__ __launch_bounds__(256) void agg_kernel(
    const int* __restrict__ off, const int* __restrict__ csr,
    const float* __restrict__ dis, const __half* __restrict__ hp,
    const float* __restrict__ bias, float* __restrict__ out, int N)
{
    constexpr int GL = C / 8;
    constexpr int G  = 64 / GL;
    const int wv   = threadIdx.x >> 6;
    const int lane = threadIdx.x & 63;
    const int grp  = lane / GL;
    const int gl   = lane % GL;
    const int node = blockIdx.x * 4 + wv;
    if (node >= N) return;

    const int s0 = off[node];
    const int s1 = off[node + 1];

    float acc[8]  = {0, 0, 0, 0, 0, 0, 0, 0};
    float acc2[8] = {0, 0, 0, 0, 0, 0, 0, 0};

    auto accum = [](float4 v, float* a) {
        const __half2* h2 = (const __half2*)&v;
#pragma unroll
        for (int j = 0; j < 4; ++j) {
            const float2 pr = __half22float2(h2[j]);
            a[2 * j]     += pr.x;
            a[2 * j + 1] += pr.y;
        }
    };

    if (grp == 0) {
        const float4 v = *(const float4*)&hp[(size_t)node * C + gl * 8];
        accum(v, acc);
    }
    int e = s0 + grp;
    for (; e + G < s1; e += 2 * G) {
        const int sa = csr[e];
        const int sb = csr[e + G];
        const float4 va = *(const float4*)&hp[(size_t)sa * C + gl * 8];
        const float4 vb = *(const float4*)&hp[(size_t)sb * C + gl * 8];
        accum(va, acc);
        accum(vb, acc2);
    }
    if (e < s1) {
        const int sa = csr[e];
        const float4 va = *(const float4*)&hp[(size_t)sa * C + gl * 8];
        accum(va, acc);
    }
#pragma unroll
    for (int j = 0; j < 8; ++j) acc[j] += acc2[j];

#pragma unroll
    for (int d = GL; d < 64; d <<= 1) {
#pragma unroll
        for (int j = 0; j < 8; ++j) acc[j] += __shfl_xor(acc[j], d);
    }

    if (grp == 0) {
        const float dn = dis[node];
        float v[8];
#pragma unroll
        for (int j = 0; j < 8; ++j) {
            v[j] = fmaf(dn, acc[j], bias[gl * 8 + j]);
            if (RELU) v[j] = fmaxf(v[j], 0.f);
        }
        *(float4*)&out[(size_t)node * C + gl * 8]     = make_float4(v[0], v[1], v[2], v[3]);
        *(float4*)&out[(size_t)node * C + gl * 8 + 4] = make_float4(v[4], v[5], v[6], v[7]);
    }
}

static inline size_t align_up(size_t x) { return (x + 255) & ~(size_t)255; }

extern "C" void kernel_launch(void* const* d_in, const int* in_sizes, int n_in,
                              void* d_out, int out_size, void* d_ws, size_t ws_size,
                              hipStream_t stream) {
    const float* x   = (const float*)d_in[0];
    const int*  eidx = (const int*)d_in[1];
    const float* W1  = (const float*)d_in[2];
    const float* b1  = (const float*)d_in[3];
    const float* W2  = (const float*)d_in[4];
    const float* b2  = (const float*)d_in[5];
    const float* W3  = (const float*)d_in[6];
    const float* b3  = (const float*)d_in[7];
    float* out = (float*)d_out;

    const int N = in_sizes[0] / 128;   // 50000 (< 65536 required for packing)
    const int E = in_sizes[1] / 2;     // 800000
    const int* srcp = eidx;
    const int* dstp = eidx + E;
    const int nbuckets = (N + 255) >> 8;   // 196

    char* ws = (char*)d_ws;
    size_t o = 0;
    float* dis   = (float*)(ws + o);  o = align_up(o + (size_t)N * 4);
    int* off     = (int*)(ws + o);    o = align_up(o + (size_t)(N + 1) * 4);
    int* btot    = (int*)(ws + o);    o = align_up(o + 256 * 4);
    int* hist    = (int*)(ws + o);    o = align_up(o + 256 * 256 * 4);
    int* bedge   = (int*)(ws + o);    o = align_up(o + (size_t)E * 4);
    int* csr     = (int*)(ws + o);    o = align_up(o + (size_t)E * 4);
    __half* H1   = (__half*)(ws + o); o = align_up(o + (size_t)N * 64 * 2);  // also reused for H3
    __half* H2   = (__half*)(ws + o); o = align_up(o + (size_t)N * 64 * 2);
    __half* H3   = H1;   // H1 dead after fused2 completes (separate dispatch)

    const dim3 blk(256);

    // --- CSR build (4 dispatches, no global atomics) ---
    part_hist_kernel<<<dim3(256), blk, 0, stream>>>(dstp, hist, E, nbuckets);
    part_scan_kernel<<<dim3(nbuckets), blk, 0, stream>>>(hist, btot);
    part_scatter_kernel<<<dim3(256), blk, 0, stream>>>(srcp, dstp, hist, btot, bedge, E, nbuckets);
    bucket_csr_kernel<<<dim3(nbuckets), blk, 0, stream>>>(bedge, btot, csr, off, dis, N, nbuckets);

    // --- layer 1 GEMM: x[128] @ W1 -> H1 (fp16, *dis) ---
    gemm_scale_kernel<128, 64, 2><<<dim3((N + 31) / 32), blk, 0, stream>>>(x, W1, dis, H1, N);

    // --- fused agg1(relu,b1) + gemm2 -> H2 (fp16, *dis) ---
    fused_agg_gemm_kernel<64><<<dim3((N + 15) / 16), blk, 0, stream>>>(
        off, csr, dis, H1, b1, W2, H2, N);

    // --- fused agg2(relu,b2) + gemm3 -> H3 (fp16 32-ch, *dis) ---
    fused_agg_gemm_kernel<32><<<dim3((N + 31) / 32), blk, 0, stream>>>(
        off, csr, dis, H2, b2, W3, H3, N);

    // --- final agg3 (+b3, no relu) -> out (fp32) ---
    agg_kernel<32, false><<<dim3((N + 3) / 4), blk, 0, stream>>>(off, csr, dis, H3, b3, out, N);
}